// Round 11
// baseline (885.396 us; speedup 1.0000x reference)
//
#include <hip/hip_runtime.h>

#define TT 2048
#define BB 256
#define II 64
#define HH 128
#define CHP 16          // x/gx chunk depth in timesteps
#define NCH (TT / CHP)  // 128 chunks
#define GXS 532         // gx row stride in floats (slot = col*4 + gate, padded)

#define LOG2E  1.4426950408889634f
#define LOG2E2 2.8853900817779268f

typedef __fp16 f16;
typedef __fp16 h2  __attribute__((ext_vector_type(2)));
typedef __fp16 v8h __attribute__((ext_vector_type(8)));
typedef float  v4f __attribute__((ext_vector_type(4)));
typedef int    v4i __attribute__((ext_vector_type(4)));

union HI { int i; h2 h; };
__device__ __forceinline__ h2  i2h(int v) { HI u; u.i = v; return u.h; }
__device__ __forceinline__ int h2i(h2 v)  { HI u; u.h = v; return u.i; }

// v_exp_f32 computes 2^x natively.
__device__ __forceinline__ float fexp2(float x) {
  float r; asm("v_exp_f32 %0, %1" : "=v"(r) : "v"(x)); return r;
}
__device__ __forceinline__ float fsig(float x) {
  return __builtin_amdgcn_rcpf(1.0f + __expf(-x));
}

// Raw barrier: LDS-drain only; global loads/stores stay in flight.
__device__ __forceinline__ void bar_lgkm() {
  asm volatile("s_waitcnt lgkmcnt(0)\n\ts_barrier" ::: "memory");
}

// One block per batch row, 512 threads = 8 waves = 2 waves/SIMD (proven
// envelope). WAVE SPECIALIZATION:
//   waves 0-3 COMPUTE (1/SIMD): own 32 cols each (ct=0,1 tiles). Minimal
//     stream: 2 af ds_reads -> 12 i8 MFMAs -> 2 gx ds_reads -> dual epilogue
//     -> 2 hq8 writes (+2 hh f16 stores, CLS==0) -> barrier.
//   waves 4-7 HELPER (1/SIMD): gx precompute (they hold the f16 Wi frags;
//     2 MFMAs/step spread over sc0-7), x global loads (sc==0) + LDS staging
//     (sc==15), CLS==1 fallback classifier on wave 4. All helper outputs are
//     consumed >=8 barrier-separated steps later -> nothing enters the
//     per-step critical chain; helpers fill SIMD issue gaps.
// Per-SIMD pipe stays 12 i8 slices (~240cyc). R10 lesson applied: no extra
// MFMAs or serial chains on compute waves; classifier via hh + gru_cls.
// All 8 waves hit bar_lgkm exactly once per step (no divergent barriers).
template <int CLS>
__global__ __launch_bounds__(512, 1) void gru_mfma(
    const float* __restrict__ x,
    const float* __restrict__ Wir, const float* __restrict__ Wiz, const float* __restrict__ Win,
    const float* __restrict__ bir, const float* __restrict__ biz, const float* __restrict__ bin_,
    const float* __restrict__ Whr, const float* __restrict__ Whz, const float* __restrict__ Whn,
    const float* __restrict__ bhn, const float* __restrict__ Wc,  const float* __restrict__ bc,
    f16* __restrict__ hh, float* __restrict__ out)
{
  const int t = threadIdx.x, b = blockIdx.x;
  const int w = t >> 6;     // wave id 0..7
  const int l = t & 63;     // lane
  const int q = l >> 4;     // quad
  const int r = l & 15;
  const bool isC = (w < 4); // compute wave?
  const int hw = w & 3;     // col-group index (compute: w; helper: w-4)

  __shared__ __attribute__((aligned(16))) signed char hq8[2][HH];  // i8 h, dbuf
  __shared__ __attribute__((aligned(16))) f16   xch[2][CHP][72];   // x chunks (f16, A-layout)
  __shared__ __attribute__((aligned(16))) float gxb[2][CHP][GXS];  // gx (prescaled), dbuf

  // ---- compute-wave state: i8 Wh frags for 2 col-tiles ----
  // frag f, byte j <-> k = 64f + 16q + j (self-consistent A/B k-slot map)
  v4i bqr[2][2], bqz[2][2], bqn[2][2];
  float invR[2], invZ[2], invN[2], bhnc[2];
  // ---- helper-wave state: f16 Wi frags for 2 col-tiles (prescaled) ----
  v8h hwr[2][2], hwz[2][2], hwn[2][2];
  float birc[2], bizc[2], binc[2];
  float wcA = 0.f, wcB = 0.f, bc0 = 0.f;

  if (isC) {
    for (int ct = 0; ct < 2; ++ct) {
      const int n = 32 * w + 16 * ct + r;
      float mr = 1e-20f, mz = 1e-20f, mn = 1e-20f;
      for (int f = 0; f < 2; ++f)
        for (int j = 0; j < 16; ++j) {
          const int k = 64 * f + 16 * q + j;
          mr = fmaxf(mr, fabsf(Whr[k * HH + n]));
          mz = fmaxf(mz, fabsf(Whz[k * HH + n]));
          mn = fmaxf(mn, fabsf(Whn[k * HH + n]));
        }
      // lanes sharing col n differ only in q: reduce over xor 16/32
      mr = fmaxf(mr, __shfl_xor(mr, 16, 64)); mr = fmaxf(mr, __shfl_xor(mr, 32, 64));
      mz = fmaxf(mz, __shfl_xor(mz, 16, 64)); mz = fmaxf(mz, __shfl_xor(mz, 32, 64));
      mn = fmaxf(mn, __shfl_xor(mn, 16, 64)); mn = fmaxf(mn, __shfl_xor(mn, 32, 64));
      const float sr = 127.f / mr, sz = 127.f / mz, sn = 127.f / mn;
      invR[ct] = LOG2E  * mr / 16129.f;   // 127^2
      invZ[ct] = LOG2E  * mz / 16129.f;
      invN[ct] = LOG2E2 * mn / 16129.f;
      bhnc[ct] = LOG2E2 * bhn[n];
      for (int f = 0; f < 2; ++f) {
        union { signed char c[16]; v4i v; } ur, uz, un;
        for (int j = 0; j < 16; ++j) {
          const int k = 64 * f + 16 * q + j;
          ur.c[j] = (signed char)(int)rintf(Whr[k * HH + n] * sr);
          uz.c[j] = (signed char)(int)rintf(Whz[k * HH + n] * sz);
          un.c[j] = (signed char)(int)rintf(Whn[k * HH + n] * sn);
        }
        bqr[ct][f] = ur.v; bqz[ct][f] = uz.v; bqn[ct][f] = un.v;
      }
    }
  } else {
    for (int ct = 0; ct < 2; ++ct) {
      const int n = 32 * hw + 16 * ct + r;
      for (int kt = 0; kt < 2; ++kt) {
        v8h vr, vz, vn;
        for (int j = 0; j < 8; ++j) {
          const int kg = 32 * kt + 8 * q + j;
          vr[j] = (f16)(LOG2E  * Wir[kg * HH + n]);
          vz[j] = (f16)(LOG2E  * Wiz[kg * HH + n]);
          vn[j] = (f16)(LOG2E2 * Win[kg * HH + n]);
        }
        hwr[ct][kt] = vr; hwz[ct][kt] = vz; hwn[ct][kt] = vn;
      }
      birc[ct] = LOG2E * bir[n]; bizc[ct] = LOG2E * biz[n]; binc[ct] = LOG2E2 * bin_[n];
    }
    if (CLS == 1 && w == 4) {
      wcA = Wc[2 * l] / 127.f; wcB = Wc[2 * l + 1] / 127.f; bc0 = bc[0];
    }
  }

  // helper full gx precompute (prologue only): 16 ts packed into M;
  // A[ts=r][k=8q+j(+32)]; C[ts=4q+j][col]. Bias folded as acc init.
  auto precomp_full = [&](int pn, v8h ax0, v8h ax1) {
    #pragma unroll
    for (int ct = 0; ct < 2; ++ct) {
      const int n = 32 * hw + 16 * ct + r;
      v4f cr = {birc[ct], birc[ct], birc[ct], birc[ct]};
      v4f cz = {bizc[ct], bizc[ct], bizc[ct], bizc[ct]};
      v4f cn = {binc[ct], binc[ct], binc[ct], binc[ct]};
      cr = __builtin_amdgcn_mfma_f32_16x16x32_f16(ax0, hwr[ct][0], cr, 0, 0, 0);
      cz = __builtin_amdgcn_mfma_f32_16x16x32_f16(ax0, hwz[ct][0], cz, 0, 0, 0);
      cn = __builtin_amdgcn_mfma_f32_16x16x32_f16(ax0, hwn[ct][0], cn, 0, 0, 0);
      cr = __builtin_amdgcn_mfma_f32_16x16x32_f16(ax1, hwr[ct][1], cr, 0, 0, 0);
      cz = __builtin_amdgcn_mfma_f32_16x16x32_f16(ax1, hwz[ct][1], cz, 0, 0, 0);
      cn = __builtin_amdgcn_mfma_f32_16x16x32_f16(ax1, hwn[ct][1], cn, 0, 0, 0);
      #pragma unroll
      for (int j = 0; j < 4; ++j) {
        v4f pk; pk[0] = cr[j]; pk[1] = cz[j]; pk[2] = cn[j]; pk[3] = 0.f;
        *(v4f*)&gxb[pn][4 * q + j][n * 4] = pk;
      }
    }
  };

  // ---- prologue: x chunks 0,1 -> LDS (all 512 threads); gx chunk 0 ----
  {
    const int pxr = t >> 5, pxc = (t & 31) * 2;
    float2 xA = *(const float2*)(x + ((size_t)(0   + pxr) * BB + b) * II + pxc);
    float2 xB = *(const float2*)(x + ((size_t)(CHP + pxr) * BB + b) * II + pxc);
    if (t < HH) { hq8[0][t] = 0; hq8[1][t] = 0; }
    *(int*)&xch[0][pxr][pxc] = h2i(__builtin_amdgcn_cvt_pkrtz(xA.x, xA.y));
    __syncthreads();
    if (!isC) {
      v8h a0x = *(const v8h*)&xch[0][r][8 * q];
      v8h a1x = *(const v8h*)&xch[0][r][32 + 8 * q];
      precomp_full(0, a0x, a1x);
    }
    *(int*)&xch[1][pxr][pxc] = h2i(__builtin_amdgcn_cvt_pkrtz(xB.x, xB.y));
    __syncthreads();
  }

  // compute-wave gx prefetch registers (step 0)
  v4f gp0 = {0.f, 0.f, 0.f, 0.f}, gp1 = {0.f, 0.f, 0.f, 0.f};
  if (isC) {
    gp0 = *(const v4f*)&gxb[0][0][(32 * w + r) * 4];
    gp1 = *(const v4f*)&gxb[0][0][(32 * w + 16 + r) * 4];
  }

  v4i ai0 = {0, 0, 0, 0}, ai1 = {0, 0, 0, 0};   // non-(r==0) lanes stay zero
  float hst[2] = {0.f, 0.f};
  f16* hup = (CLS == 0) ? (hh + (size_t)b * HH) : nullptr;  // uniform rolling base
  v4f cpr, cpz, cpn;                            // helper spread-precomp accs
  v8h ax0 = {}, ax1 = {};                       // helper chunk-top A frags
  float4 xr;                                    // helper staging regs
  const int hxr = (t >> 4) & 15, hxc = (t & 15) * 4;  // helper staging coords
  const v4i zi = {0, 0, 0, 0};

  for (int c = 0; c < NCH; ++c) {
    const int p = c & 1;
    const bool pc = (c + 1 < NCH);   // precompute gx for next chunk?
    const bool ld = (c + 2 < NCH);   // load x for chunk after next?

    if (!isC) {
      if (pc) {
        ax0 = *(const v8h*)&xch[p ^ 1][r][8 * q];
        ax1 = *(const v8h*)&xch[p ^ 1][r][32 + 8 * q];
      }
      if (ld) {
        xr = *(const float4*)(x + ((size_t)((c + 2) * CHP + hxr) * BB + b) * II + hxc);
      }
    }

    #pragma unroll
    for (int sc = 0; sc < CHP; ++sc) {
      const int s = c * CHP + sc;          // affine; sc is a literal
      const int cur = sc & 1, nxt = cur ^ 1;

      if (isC) {
        // ---------------- COMPUTE ----------------
        if (r == 0) {
          ai0 = *(const v4i*)&hq8[cur][16 * q];
          ai1 = *(const v4i*)&hq8[cur][64 + 16 * q];
        }

        // 12 i8 MFMAs: 6 independent on ai0, then 6 on ai1 (dep distance 6)
        v4i cr0, cr1, cn0, cn1, cz0, cz1;
        cr0 = __builtin_amdgcn_mfma_i32_16x16x64_i8(ai0, bqr[0][0], zi, 0, 0, 0);
        cr1 = __builtin_amdgcn_mfma_i32_16x16x64_i8(ai0, bqr[1][0], zi, 0, 0, 0);
        cn0 = __builtin_amdgcn_mfma_i32_16x16x64_i8(ai0, bqn[0][0], zi, 0, 0, 0);
        cn1 = __builtin_amdgcn_mfma_i32_16x16x64_i8(ai0, bqn[1][0], zi, 0, 0, 0);
        cz0 = __builtin_amdgcn_mfma_i32_16x16x64_i8(ai0, bqz[0][0], zi, 0, 0, 0);
        cz1 = __builtin_amdgcn_mfma_i32_16x16x64_i8(ai0, bqz[1][0], zi, 0, 0, 0);
        cr0 = __builtin_amdgcn_mfma_i32_16x16x64_i8(ai1, bqr[0][1], cr0, 0, 0, 0);
        cr1 = __builtin_amdgcn_mfma_i32_16x16x64_i8(ai1, bqr[1][1], cr1, 0, 0, 0);
        cn0 = __builtin_amdgcn_mfma_i32_16x16x64_i8(ai1, bqn[0][1], cn0, 0, 0, 0);
        cn1 = __builtin_amdgcn_mfma_i32_16x16x64_i8(ai1, bqn[1][1], cn1, 0, 0, 0);
        cz0 = __builtin_amdgcn_mfma_i32_16x16x64_i8(ai1, bqz[0][1], cz0, 0, 0, 0);
        cz1 = __builtin_amdgcn_mfma_i32_16x16x64_i8(ai1, bqz[1][1], cz1, 0, 0, 0);

        // gx for THIS step (prefetched); prefetch next step's now
        const v4f g0 = gp0, g1 = gp1;
        if (sc < CHP - 1) {
          gp0 = *(const v4f*)&gxb[p][sc + 1][(32 * w + r) * 4];
          gp1 = *(const v4f*)&gxb[p][sc + 1][(32 * w + 16 + r) * 4];
        } else if (c + 1 < NCH) {
          gp0 = *(const v4f*)&gxb[p ^ 1][0][(32 * w + r) * 4];
          gp1 = *(const v4f*)&gxb[p ^ 1][0][(32 * w + 16 + r) * 4];
        }

        // dual epilogue: C row 0 = elem 0 of q==0 lanes; cols 32w+r, +16
        if (q == 0) {
          {
            const float arS = (float)cr0[0] * invR[0] + g0[0];
            const float rr  = __builtin_amdgcn_rcpf(1.f + fexp2(-arS));
            const float anS = (float)cn0[0] * invN[0] + bhnc[0];
            const float nn  = 1.f - 2.f * __builtin_amdgcn_rcpf(1.f + fexp2(g0[2] + rr * anS));
            const float azS = (float)cz0[0] * invZ[0] + g0[1];
            const float zz  = __builtin_amdgcn_rcpf(1.f + fexp2(-azS));
            hst[0] = nn + zz * (hst[0] - nn);
            hq8[nxt][32 * w + r] = (signed char)(int)rintf(hst[0] * 127.f);
            if (CLS == 0) hup[32 * w + r] = (f16)hst[0];
          }
          {
            const float arS = (float)cr1[0] * invR[1] + g1[0];
            const float rr  = __builtin_amdgcn_rcpf(1.f + fexp2(-arS));
            const float anS = (float)cn1[0] * invN[1] + bhnc[1];
            const float nn  = 1.f - 2.f * __builtin_amdgcn_rcpf(1.f + fexp2(g1[2] + rr * anS));
            const float azS = (float)cz1[0] * invZ[1] + g1[1];
            const float zz  = __builtin_amdgcn_rcpf(1.f + fexp2(-azS));
            hst[1] = nn + zz * (hst[1] - nn);
            hq8[nxt][32 * w + 16 + r] = (signed char)(int)rintf(hst[1] * 127.f);
            if (CLS == 0) hup[32 * w + 16 + r] = (f16)hst[1];
          }
        }
        if (CLS == 0) hup += BB * HH;          // uniform -> SALU roll
      } else {
        // ---------------- HELPER ----------------
        // spread gx precompute: <=2 MFMAs or 4 LDS stores per step
        if (pc) {
          if (sc == 0) {
            v4f i0 = {birc[0], birc[0], birc[0], birc[0]};
            v4f i1 = {bizc[0], bizc[0], bizc[0], bizc[0]};
            cpr = __builtin_amdgcn_mfma_f32_16x16x32_f16(ax0, hwr[0][0], i0, 0, 0, 0);
            cpz = __builtin_amdgcn_mfma_f32_16x16x32_f16(ax0, hwz[0][0], i1, 0, 0, 0);
          } else if (sc == 1) {
            v4f i2 = {binc[0], binc[0], binc[0], binc[0]};
            cpn = __builtin_amdgcn_mfma_f32_16x16x32_f16(ax0, hwn[0][0], i2, 0, 0, 0);
            cpr = __builtin_amdgcn_mfma_f32_16x16x32_f16(ax1, hwr[0][1], cpr, 0, 0, 0);
          } else if (sc == 2) {
            cpz = __builtin_amdgcn_mfma_f32_16x16x32_f16(ax1, hwz[0][1], cpz, 0, 0, 0);
            cpn = __builtin_amdgcn_mfma_f32_16x16x32_f16(ax1, hwn[0][1], cpn, 0, 0, 0);
          } else if (sc == 3) {
            const int n = 32 * hw + r;
            #pragma unroll
            for (int j = 0; j < 4; ++j) {
              v4f pk; pk[0] = cpr[j]; pk[1] = cpz[j]; pk[2] = cpn[j]; pk[3] = 0.f;
              *(v4f*)&gxb[p ^ 1][4 * q + j][n * 4] = pk;
            }
          } else if (sc == 4) {
            v4f i0 = {birc[1], birc[1], birc[1], birc[1]};
            v4f i1 = {bizc[1], bizc[1], bizc[1], bizc[1]};
            cpr = __builtin_amdgcn_mfma_f32_16x16x32_f16(ax0, hwr[1][0], i0, 0, 0, 0);
            cpz = __builtin_amdgcn_mfma_f32_16x16x32_f16(ax0, hwz[1][0], i1, 0, 0, 0);
          } else if (sc == 5) {
            v4f i2 = {binc[1], binc[1], binc[1], binc[1]};
            cpn = __builtin_amdgcn_mfma_f32_16x16x32_f16(ax0, hwn[1][0], i2, 0, 0, 0);
            cpr = __builtin_amdgcn_mfma_f32_16x16x32_f16(ax1, hwr[1][1], cpr, 0, 0, 0);
          } else if (sc == 6) {
            cpz = __builtin_amdgcn_mfma_f32_16x16x32_f16(ax1, hwz[1][1], cpz, 0, 0, 0);
            cpn = __builtin_amdgcn_mfma_f32_16x16x32_f16(ax1, hwn[1][1], cpn, 0, 0, 0);
          } else if (sc == 7) {
            const int n = 32 * hw + 16 + r;
            #pragma unroll
            for (int j = 0; j < 4; ++j) {
              v4f pk; pk[0] = cpr[j]; pk[1] = cpz[j]; pk[2] = cpn[j]; pk[3] = 0.f;
              *(v4f*)&gxb[p ^ 1][4 * q + j][n * 4] = pk;
            }
          }
        }
        // stage chunk c+2's x into xch[p] (current chunk's slot now free)
        if (sc == CHP - 1 && ld) {
          int2 pv;
          pv.x = h2i(__builtin_amdgcn_cvt_pkrtz(xr.x, xr.y));
          pv.y = h2i(__builtin_amdgcn_cvt_pkrtz(xr.z, xr.w));
          *(int2*)&xch[p][hxr][hxc] = pv;
        }
        // CLS==1 fallback: wave 4 classifies h_{s-1} from hq8[cur] (i8).
        // Serial shfl chain lives on an otherwise-idle helper stream.
        if (CLS == 1 && w == 4 && (sc > 0 || c > 0)) {
          const int hv = *(const short*)&hq8[cur][2 * l];
          float cred = (float)((hv << 24) >> 24) * wcA + (float)(hv >> 8) * wcB;
          cred += __shfl_xor(cred, 1, 64);
          cred += __shfl_xor(cred, 2, 64);
          cred += __shfl_xor(cred, 4, 64);
          cred += __shfl_xor(cred, 8, 64);
          cred += __shfl_xor(cred, 16, 64);
          cred += __shfl_xor(cred, 32, 64);
          if (l == 0) out[(size_t)(s - 1) * BB + b] = fsig(cred + bc0);
        }
      }

      bar_lgkm();
    }
  }

  // CLS==1 tail: h_{TT-1} is in hq8[0] (step 2047 wrote nxt==0)
  if (CLS == 1 && w == 4) {
    const int hv = *(const short*)&hq8[0][2 * l];
    float cred = (float)((hv << 24) >> 24) * wcA + (float)(hv >> 8) * wcB;
    cred += __shfl_xor(cred, 1, 64);
    cred += __shfl_xor(cred, 2, 64);
    cred += __shfl_xor(cred, 4, 64);
    cred += __shfl_xor(cred, 8, 64);
    cred += __shfl_xor(cred, 16, 64);
    cred += __shfl_xor(cred, 32, 64);
    if (l == 0) out[(size_t)(TT - 1) * BB + b] = fsig(cred + bc0);
  }
}

// out[row] = sigmoid(dot(hh[row][:], Wc) + bc); row = t*BB + b. hh is f16.
// 4 threads per row (32 cols each), 64 rows/block, coalesced 16B reads.
__global__ __launch_bounds__(256) void gru_cls(
    const f16* __restrict__ hh, const float* __restrict__ Wc,
    const float* __restrict__ bc, float* __restrict__ out)
{
  const int t  = threadIdx.x;
  const int g4 = t & 3;
  const size_t row = (size_t)blockIdx.x * 64 + (t >> 2);
  const f16* hp = hh + row * HH + 32 * g4;
  const float* wp = Wc + 32 * g4;
  float acc = 0.f;
  #pragma unroll
  for (int i = 0; i < 4; ++i) {
    v8h h8 = *(const v8h*)(hp + 8 * i);
    const float* wq = wp + 8 * i;
    #pragma unroll
    for (int j = 0; j < 8; ++j) acc += (float)h8[j] * wq[j];
  }
  acc += __shfl_xor(acc, 1, 64);
  acc += __shfl_xor(acc, 2, 64);
  if (g4 == 0) out[row] = fsig(acc + bc[0]);
}

extern "C" void kernel_launch(void* const* d_in, const int* in_sizes, int n_in,
                              void* d_out, int out_size, void* d_ws, size_t ws_size,
                              hipStream_t stream) {
  const float* x    = (const float*)d_in[0];
  const float* Wir  = (const float*)d_in[1];
  const float* Wiz  = (const float*)d_in[2];
  const float* Win  = (const float*)d_in[3];
  const float* bir  = (const float*)d_in[4];
  const float* biz  = (const float*)d_in[5];
  const float* bin_ = (const float*)d_in[6];
  const float* Whr  = (const float*)d_in[7];
  const float* Whz  = (const float*)d_in[8];
  const float* Whn  = (const float*)d_in[9];
  const float* bhn  = (const float*)d_in[10];
  const float* Wc   = (const float*)d_in[11];
  const float* bc   = (const float*)d_in[12];
  float* out = (float*)d_out;

  const size_t need = (size_t)TT * BB * HH * sizeof(f16);  // 128 MiB h history
  if (d_ws != nullptr && ws_size >= need) {
    f16* hh = (f16*)d_ws;
    gru_mfma<0><<<dim3(BB), dim3(512), 0, stream>>>(
        x, Wir, Wiz, Win, bir, biz, bin_, Whr, Whz, Whn, bhn, Wc, bc, hh, out);
    gru_cls<<<dim3((TT * BB) / 64), dim3(256), 0, stream>>>(hh, Wc, bc, out);
  } else {
    gru_mfma<1><<<dim3(BB), dim3(512), 0, stream>>>(
        x, Wir, Wiz, Win, bir, biz, bin_, Whr, Whz, Whn, bhn, Wc, bc, nullptr, out);
  }
}

// Round 12
// 767.319 us; speedup vs baseline: 1.1539x; 1.1539x over previous
//
#include <hip/hip_runtime.h>

#define TT 2048
#define BB 256
#define II 64
#define HH 128
#define CHP 16          // x/gx chunk depth in timesteps
#define NCH (TT / CHP)  // 128 chunks
#define GXS 532         // gx row stride in floats (slot = col*4 + gate, padded)

#define LOG2E  1.4426950408889634f
#define LOG2E2 2.8853900817779268f

typedef __fp16 f16;
typedef __fp16 h2  __attribute__((ext_vector_type(2)));
typedef __fp16 v8h __attribute__((ext_vector_type(8)));
typedef float  v4f __attribute__((ext_vector_type(4)));
typedef int    v4i __attribute__((ext_vector_type(4)));

union HI { int i; h2 h; };
__device__ __forceinline__ h2  i2h(int v) { HI u; u.i = v; return u.h; }
__device__ __forceinline__ int h2i(h2 v)  { HI u; u.h = v; return u.i; }

// v_exp_f32 computes 2^x natively.
__device__ __forceinline__ float fexp2(float x) {
  float r; asm("v_exp_f32 %0, %1" : "=v"(r) : "v"(x)); return r;
}
__device__ __forceinline__ float fsig(float x) {       // cls kernel only
  return __builtin_amdgcn_rcpf(1.0f + __expf(-x));
}

// Raw barrier: LDS-drain only; global loads/stores stay in flight.
__device__ __forceinline__ void bar_lgkm() {
  asm volatile("s_waitcnt lgkmcnt(0)\n\ts_barrier" ::: "memory");
}

// One block per batch row, 512 threads = 8 waves = 2 waves/SIMD. Session-best
// structure (R8, 769.7us total): outer chunk loop x fully-unrolled 16-step
// inner loop; i8 h-projection (mfma_i32_16x16x64_i8, 2x f16 rate, pipe
// 12 slices/SIMD); gx (x-projection) precomputed per 16-step chunk by
// timestep-packed f16 MFMAs spread 1-op/step into the af-wait bubble;
// exp2-prescaled epilogue; h history streamed as f16 via uniform SGPR-base
// stores; classifier in a trivial second kernel.
// Post-R8 variants all regressed (R9 in-loop shuffle classifier +451cyc/step,
// R10 matrix classifier +56, R11 wave specialization +135): the symmetric
// 8x16-col partition with one epilogue chain per wave and 2 waves/SIMD
// co-hiding latency is the verified optimum of this family.
template <int CLS>
__global__ __launch_bounds__(512, 1) void gru_mfma(
    const float* __restrict__ x,
    const float* __restrict__ Wir, const float* __restrict__ Wiz, const float* __restrict__ Win,
    const float* __restrict__ bir, const float* __restrict__ biz, const float* __restrict__ bin_,
    const float* __restrict__ Whr, const float* __restrict__ Whz, const float* __restrict__ Whn,
    const float* __restrict__ bhn, const float* __restrict__ Wc,  const float* __restrict__ bc,
    f16* __restrict__ hh, float* __restrict__ out)
{
  const int t = threadIdx.x, b = blockIdx.x;
  const int w = t >> 6;     // wave id 0..7
  const int l = t & 63;     // lane
  const int q = l >> 4;     // quad
  const int r = l & 15;
  const int nc = 16 * w + r;   // this lane's output column

  __shared__ __attribute__((aligned(16))) signed char hq8[2][HH];  // i8 h, dbuf
  __shared__ __attribute__((aligned(16))) f16   xch[2][CHP][72];   // x chunks (f16, A-layout)
  __shared__ __attribute__((aligned(16))) float gxb[2][CHP][GXS];  // gx (prescaled), dbuf
  __shared__ float cpart[2][128];                                   // CLS==1 classifier partials

  // ---- i8 Wh fragments: frag f, byte j  <->  k = 64f + 16q + j ----
  v4i bqr[2], bqz[2], bqn[2];
  float invR, invZ, invN;
  {
    // per-column max |W|: lane sees 32 of 128 k per gate; lanes sharing
    // column nc differ only in q -> reduce over xor 16/32.
    float mr = 1e-20f, mz = 1e-20f, mn = 1e-20f;
    for (int f = 0; f < 2; ++f)
      for (int j = 0; j < 16; ++j) {
        const int k = 64 * f + 16 * q + j;
        mr = fmaxf(mr, fabsf(Whr[k * HH + nc]));
        mz = fmaxf(mz, fabsf(Whz[k * HH + nc]));
        mn = fmaxf(mn, fabsf(Whn[k * HH + nc]));
      }
    mr = fmaxf(mr, __shfl_xor(mr, 16, 64)); mr = fmaxf(mr, __shfl_xor(mr, 32, 64));
    mz = fmaxf(mz, __shfl_xor(mz, 16, 64)); mz = fmaxf(mz, __shfl_xor(mz, 32, 64));
    mn = fmaxf(mn, __shfl_xor(mn, 16, 64)); mn = fmaxf(mn, __shfl_xor(mn, 32, 64));
    const float sr = 127.f / mr, sz = 127.f / mz, sn = 127.f / mn;
    invR = LOG2E  * mr / 16129.f;   // 127^2
    invZ = LOG2E  * mz / 16129.f;
    invN = LOG2E2 * mn / 16129.f;
    for (int f = 0; f < 2; ++f) {
      union { signed char c[16]; v4i v; } ur, uz, un;
      for (int j = 0; j < 16; ++j) {
        const int k = 64 * f + 16 * q + j;
        ur.c[j] = (signed char)(int)rintf(Whr[k * HH + nc] * sr);
        uz.c[j] = (signed char)(int)rintf(Whz[k * HH + nc] * sz);
        un.c[j] = (signed char)(int)rintf(Whn[k * HH + nc] * sn);
      }
      bqr[f] = ur.v; bqz[f] = uz.v; bqn[f] = un.v;
    }
  }

  // ---- f16 Wi fragments for the gx precompute (log2e-prescaled) ----
  v8h wir[2], wiz[2], win2[2];
  for (int kt = 0; kt < 2; ++kt) {
    v8h vr, vz, vn;
    for (int j = 0; j < 8; ++j) {
      const int kg = 32 * kt + 8 * q + j;
      vr[j] = (f16)(LOG2E  * Wir[kg * HH + nc]);
      vz[j] = (f16)(LOG2E  * Wiz[kg * HH + nc]);
      vn[j] = (f16)(LOG2E2 * Win[kg * HH + nc]);
    }
    wir[kt] = vr; wiz[kt] = vz; win2[kt] = vn;
  }

  const float birc = LOG2E * bir[nc],  bizc = LOG2E * biz[nc];
  const float binc = LOG2E2 * bin_[nc], bhnc = LOG2E2 * bhn[nc];
  float wc = 0.f, bc0 = 0.f;
  if (CLS == 1) { wc = Wc[nc]; bc0 = bc[0]; }

  // full gx precompute (prologue only): 16 timesteps packed into M;
  // A[ts=r][k=8q+j (+32 for ax1)]; C[ts=4q+j][col=nc]. Bias = acc init.
  auto precomp_full = [&](int pn, v8h ax0, v8h ax1) {
    v4f cr = {birc, birc, birc, birc};
    v4f cz = {bizc, bizc, bizc, bizc};
    v4f cn = {binc, binc, binc, binc};
    cr = __builtin_amdgcn_mfma_f32_16x16x32_f16(ax0, wir[0],  cr, 0, 0, 0);
    cz = __builtin_amdgcn_mfma_f32_16x16x32_f16(ax0, wiz[0],  cz, 0, 0, 0);
    cn = __builtin_amdgcn_mfma_f32_16x16x32_f16(ax0, win2[0], cn, 0, 0, 0);
    cr = __builtin_amdgcn_mfma_f32_16x16x32_f16(ax1, wir[1],  cr, 0, 0, 0);
    cz = __builtin_amdgcn_mfma_f32_16x16x32_f16(ax1, wiz[1],  cz, 0, 0, 0);
    cn = __builtin_amdgcn_mfma_f32_16x16x32_f16(ax1, win2[1], cn, 0, 0, 0);
    #pragma unroll
    for (int j = 0; j < 4; ++j) {
      v4f pk; pk[0] = cr[j]; pk[1] = cz[j]; pk[2] = cn[j]; pk[3] = 0.f;
      *(v4f*)&gxb[pn][4 * q + j][nc * 4] = pk;
    }
  };

  // ---- prologue: x chunks 0,1 -> LDS; gx chunk 0 ----
  const int xrow = t >> 5, xcol = (t & 31) * 2;   // thread covers 2 f32 of one row
  float2 xr;
  {
    float2 xA = *(const float2*)(x + ((size_t)(0   + xrow) * BB + b) * II + xcol);
    float2 xB = *(const float2*)(x + ((size_t)(CHP + xrow) * BB + b) * II + xcol);
    if (t < HH) { hq8[0][t] = 0; hq8[1][t] = 0; }
    *(int*)&xch[0][xrow][xcol] = h2i(__builtin_amdgcn_cvt_pkrtz(xA.x, xA.y));
    __syncthreads();
    {
      v8h a0x = *(const v8h*)&xch[0][r][8 * q];
      v8h a1x = *(const v8h*)&xch[0][r][32 + 8 * q];
      precomp_full(0, a0x, a1x);
    }
    *(int*)&xch[1][xrow][xcol] = h2i(__builtin_amdgcn_cvt_pkrtz(xB.x, xB.y));
    __syncthreads();
  }

  // gx prefetch register (step 0)
  v4f gp = *(const v4f*)&gxb[0][0][nc * 4];

  v4i ai0 = {0, 0, 0, 0}, ai1 = {0, 0, 0, 0};   // non-(r==0) lanes stay zero
  float hst = 0.f;
  f16* hup = (CLS == 0) ? (hh + (size_t)b * HH) : nullptr;  // UNIFORM rolling base
  v4f cpr, cpz, cpn;                                        // spread-precomp accs

  for (int c = 0; c < NCH; ++c) {
    const int p = c & 1;
    const bool pc = (c + 1 < NCH);   // precompute gx for next chunk?
    const bool ld = (c + 2 < NCH);   // load x for chunk after next?

    // chunk-top reads: ax frags for the spread precompute; global x loads for
    // chunk c+2 (15 steps of latency slack).
    v8h ax0 = {}, ax1 = {};
    if (pc) {
      ax0 = *(const v8h*)&xch[p ^ 1][r][8 * q];
      ax1 = *(const v8h*)&xch[p ^ 1][r][32 + 8 * q];
    }
    if (ld) {
      xr = *(const float2*)(x + ((size_t)((c + 2) * CHP + xrow) * BB + b) * II + xcol);
    }

    #pragma unroll
    for (int sc = 0; sc < CHP; ++sc) {
      const int s = c * CHP + sc;          // affine; sc is a literal
      const int cur = sc & 1, nxt = cur ^ 1;

      // i8 h A-frags (2 reads, r==0 lanes; 16B-aligned)
      if (r == 0) {
        ai0 = *(const v4i*)&hq8[cur][16 * q];
        ai1 = *(const v4i*)&hq8[cur][64 + 16 * q];
      }

      // spread gx precompute: one op per step in the af-wait bubble.
      if (pc) {
        if (sc == 0) {
          v4f ir = {birc, birc, birc, birc};
          cpr = __builtin_amdgcn_mfma_f32_16x16x32_f16(ax0, wir[0], ir, 0, 0, 0);
        } else if (sc == 1) {
          v4f iz = {bizc, bizc, bizc, bizc};
          cpz = __builtin_amdgcn_mfma_f32_16x16x32_f16(ax0, wiz[0], iz, 0, 0, 0);
        } else if (sc == 2) {
          v4f in_ = {binc, binc, binc, binc};
          cpn = __builtin_amdgcn_mfma_f32_16x16x32_f16(ax0, win2[0], in_, 0, 0, 0);
        } else if (sc == 3) {
          cpr = __builtin_amdgcn_mfma_f32_16x16x32_f16(ax1, wir[1], cpr, 0, 0, 0);
        } else if (sc == 4) {
          cpz = __builtin_amdgcn_mfma_f32_16x16x32_f16(ax1, wiz[1], cpz, 0, 0, 0);
        } else if (sc == 5) {
          cpn = __builtin_amdgcn_mfma_f32_16x16x32_f16(ax1, win2[1], cpn, 0, 0, 0);
        } else if (sc >= 6 && sc < 10) {
          const int j = sc - 6;
          v4f pk; pk[0] = cpr[j]; pk[1] = cpz[j]; pk[2] = cpn[j]; pk[3] = 0.f;
          *(v4f*)&gxb[p ^ 1][4 * q + j][nc * 4] = pk;
        }
      }

      // CLS==1: pick up previous step's classifier partials
      float cred = 0.f;
      if (CLS == 1 && w == 7 && (sc > 0 || c > 0))
        cred = cpart[nxt][l] + cpart[nxt][64 + l];

      // i8 MFMA phase: 2 K-halves x 3 gates, r first / n / z last.
      const v4i zi = {0, 0, 0, 0};
      v4i cr_, cn2, cz_;
      cr_ = __builtin_amdgcn_mfma_i32_16x16x64_i8(ai0, bqr[0], zi, 0, 0, 0);
      cn2 = __builtin_amdgcn_mfma_i32_16x16x64_i8(ai0, bqn[0], zi, 0, 0, 0);
      cz_ = __builtin_amdgcn_mfma_i32_16x16x64_i8(ai0, bqz[0], zi, 0, 0, 0);
      cr_ = __builtin_amdgcn_mfma_i32_16x16x64_i8(ai1, bqr[1], cr_, 0, 0, 0);
      cn2 = __builtin_amdgcn_mfma_i32_16x16x64_i8(ai1, bqn[1], cn2, 0, 0, 0);
      cz_ = __builtin_amdgcn_mfma_i32_16x16x64_i8(ai1, bqz[1], cz_, 0, 0, 0);

      // gx for THIS step (prefetched last step); prefetch next step's now.
      const v4f g = gp;
      if (sc < CHP - 1) {
        gp = *(const v4f*)&gxb[p][sc + 1][nc * 4];
      } else if (c + 1 < NCH) {
        gp = *(const v4f*)&gxb[p ^ 1][0][nc * 4];
      }

      // epilogue: C row 0 = elem 0 of quad-0 lanes; col = nc.
      // Dequant constants fold 1/127^2, per-column W scale, and log2e.
      if (q == 0) {
        const float arS = (float)cr_[0] * invR + g[0];
        const float rr  = __builtin_amdgcn_rcpf(1.f + fexp2(-arS));
        const float anS = (float)cn2[0] * invN + bhnc;
        const float nn  = 1.f - 2.f * __builtin_amdgcn_rcpf(1.f + fexp2(g[2] + rr * anS));
        const float azS = (float)cz_[0] * invZ + g[1];
        const float zz  = __builtin_amdgcn_rcpf(1.f + fexp2(-azS));
        hst = nn + zz * (hst - nn);
        hq8[nxt][nc] = (signed char)(int)rintf(hst * 127.f);   // i8 h for next step
        if (CLS == 0) hup[nc] = (f16)hst;    // saddr-form fire-and-forget store
        if (CLS == 1) cpart[cur][nc] = hst * wc;
      }
      if (CLS == 0) hup += BB * HH;          // uniform -> SALU roll

      // CLS==1: finish previous step's classifier (overlaps other waves)
      if (CLS == 1 && w == 7 && (sc > 0 || c > 0)) {
        cred += __shfl_xor(cred, 1, 64);
        cred += __shfl_xor(cred, 2, 64);
        cred += __shfl_xor(cred, 4, 64);
        cred += __shfl_xor(cred, 8, 64);
        cred += __shfl_xor(cred, 16, 64);
        cred += __shfl_xor(cred, 32, 64);
        if (l == 0) out[(size_t)(s - 1) * BB + b] = fsig(cred + bc0);
      }

      // stage chunk c+2's x (loaded at top of this chunk) into xch[p]
      if (sc == CHP - 1 && ld) {
        *(int*)&xch[p][xrow][xcol] = h2i(__builtin_amdgcn_cvt_pkrtz(xr.x, xr.y));
      }

      bar_lgkm();
    }
  }

  if (CLS == 1 && w == 7) {
    float cred = cpart[1][l] + cpart[1][64 + l];
    cred += __shfl_xor(cred, 1, 64);
    cred += __shfl_xor(cred, 2, 64);
    cred += __shfl_xor(cred, 4, 64);
    cred += __shfl_xor(cred, 8, 64);
    cred += __shfl_xor(cred, 16, 64);
    cred += __shfl_xor(cred, 32, 64);
    if (l == 0) out[(size_t)(TT - 1) * BB + b] = fsig(cred + bc0);
  }
}

// out[row] = sigmoid(dot(hh[row][:], Wc) + bc); row = t*BB + b. hh is f16.
// 4 threads per row (32 cols each), 64 rows/block, coalesced 16B reads.
__global__ __launch_bounds__(256) void gru_cls(
    const f16* __restrict__ hh, const float* __restrict__ Wc,
    const float* __restrict__ bc, float* __restrict__ out)
{
  const int t  = threadIdx.x;
  const int g4 = t & 3;
  const size_t row = (size_t)blockIdx.x * 64 + (t >> 2);
  const f16* hp = hh + row * HH + 32 * g4;
  const float* wp = Wc + 32 * g4;
  float acc = 0.f;
  #pragma unroll
  for (int i = 0; i < 4; ++i) {
    v8h h8 = *(const v8h*)(hp + 8 * i);
    const float* wq = wp + 8 * i;
    #pragma unroll
    for (int j = 0; j < 8; ++j) acc += (float)h8[j] * wq[j];
  }
  acc += __shfl_xor(acc, 1, 64);
  acc += __shfl_xor(acc, 2, 64);
  if (g4 == 0) out[row] = fsig(acc + bc[0]);
}

extern "C" void kernel_launch(void* const* d_in, const int* in_sizes, int n_in,
                              void* d_out, int out_size, void* d_ws, size_t ws_size,
                              hipStream_t stream) {
  const float* x    = (const float*)d_in[0];
  const float* Wir  = (const float*)d_in[1];
  const float* Wiz  = (const float*)d_in[2];
  const float* Win  = (const float*)d_in[3];
  const float* bir  = (const float*)d_in[4];
  const float* biz  = (const float*)d_in[5];
  const float* bin_ = (const float*)d_in[6];
  const float* Whr  = (const float*)d_in[7];
  const float* Whz  = (const float*)d_in[8];
  const float* Whn  = (const float*)d_in[9];
  const float* bhn  = (const float*)d_in[10];
  const float* Wc   = (const float*)d_in[11];
  const float* bc   = (const float*)d_in[12];
  float* out = (float*)d_out;

  const size_t need = (size_t)TT * BB * HH * sizeof(f16);  // 128 MiB h history
  if (d_ws != nullptr && ws_size >= need) {
    f16* hh = (f16*)d_ws;
    gru_mfma<0><<<dim3(BB), dim3(512), 0, stream>>>(
        x, Wir, Wiz, Win, bir, biz, bin_, Whr, Whz, Whn, bhn, Wc, bc, hh, out);
    gru_cls<<<dim3((TT * BB) / 64), dim3(256), 0, stream>>>(hh, Wc, bc, out);
  } else {
    gru_mfma<1><<<dim3(BB), dim3(512), 0, stream>>>(
        x, Wir, Wiz, Win, bir, biz, bin_, Whr, Whz, Whn, bhn, Wc, bc, nullptr, out);
  }
}